// Round 6
// baseline (51.987 us; speedup 1.0000x reference)
//
#include <hip/hip_runtime.h>
#include <hip/hip_bf16.h>
#include <math.h>

// SimpleRetention on MI355X, round 6.
// out = (Q K^T ∘ D) V, D[n,m]=gamma^(n-m)[n>=m], gamma=0.96875.
// Banded: gamma^513 ~ 8e-8 -> window of 8 previous 64-tiles + diagonal.
// proj v5: per-block xPos table in LDS (no table kernel), hi/lo 3-term MFMA.
// retention v4: K/Q global->register (no LDS), V+S double-buffered in LDS,
//               ONE barrier per tile, K prefetch pipeline, XCD swizzle.

#define SEQ    4096
#define NB     4
#define HID    256
#define HD     64
#define WT     8

typedef short          bf16x8 __attribute__((ext_vector_type(8)));
typedef float          f32x4  __attribute__((ext_vector_type(4)));
typedef unsigned short u16;
typedef unsigned int   u32;
typedef u16            u16x8  __attribute__((ext_vector_type(8)));
typedef u16            u16x4  __attribute__((ext_vector_type(4)));

__device__ __forceinline__ u16 f2bf(float f) {
    __hip_bfloat16 h = __float2bfloat16(f);
    return __builtin_bit_cast(u16, h);
}
__device__ __forceinline__ float bf2f(u16 b) {
    __hip_bfloat16 h = __builtin_bit_cast(__hip_bfloat16, b);
    return __bfloat162float(h);
}

// ---------------------------------------------------------------------------
// Prep: W fragment swizzle hi/lo only. 24 blocks x 256 thr.
// Wf frag f = ((ct*8 + kc)*64 + lane): b[j] = W[kc*32+(lane>>4)*8+j][ct*16+(lane&15)]
// ---------------------------------------------------------------------------
__global__ __launch_bounds__(256)
void prep_kernel(const float* __restrict__ WQ, const float* __restrict__ WK,
                 const float* __restrict__ WV,
                 u16* __restrict__ Wfh, u16* __restrict__ Wfl)
{
    const int p = blockIdx.x * 256 + threadIdx.x;   // 0..6143
    const int lane = p & 63;
    const int kc   = (p >> 6) & 7;
    const int ct   = p >> 9;                        // 0..11
    const int col  = ct * 16 + (lane & 15);
    const float* Wsrc = (col < 64) ? WQ : (col < 128) ? WK : WV;
    const int c = col & 63;
    u16x8 hv, lv;
#pragma unroll
    for (int j = 0; j < 8; ++j) {
        const float w = Wsrc[(kc * 32 + (lane >> 4) * 8 + j) * HD + c];
        hv[j] = f2bf(w);
        lv[j] = f2bf(w - bf2f(hv[j]));
    }
    *reinterpret_cast<u16x8*>(&Wfh[(size_t)p * 8]) = hv;
    *reinterpret_cast<u16x8*>(&Wfl[(size_t)p * 8]) = lv;
}

// ---------------------------------------------------------------------------
// Projection + fused xPos. 512 blocks x 512 thr, 32 rows/block.
// xPos table (32n x 32i) computed per block into LDS during X staging.
// ---------------------------------------------------------------------------
#define XLDS 264   // u16 row stride: 16B-aligned, 2-way bank alias (free)

__global__ __launch_bounds__(512, 4)
void proj_kernel(const float* __restrict__ X,
                 const u16* __restrict__ Wfh, const u16* __restrict__ Wfl,
                 u16* __restrict__ Qh, u16* __restrict__ Ql,
                 u16* __restrict__ Kh, u16* __restrict__ Kl,
                 u16* __restrict__ Vb)
{
    __shared__ __align__(16) u16 Xhs[32 * XLDS];
    __shared__ __align__(16) u16 Xls[32 * XLDS];
    __shared__ __align__(16) float4 Tb[32 * 32];   // [local row][i] {csQ,snQ,csK,snK}
    const int t = threadIdx.x;
    const int row0 = blockIdx.x * 32;

    // stage X tile as bf16 hi/lo (convert once per block)
    for (int e = t; e < 32 * 64; e += 512) {
        const int r = e >> 6, k4 = (e & 63) << 2;
        const float4 xv = *reinterpret_cast<const float4*>(&X[(size_t)(row0 + r) * HID + k4]);
        u16x4 hv, lv;
#pragma unroll
        for (int j = 0; j < 4; ++j) {
            const float f = (&xv.x)[j];
            hv[j] = f2bf(f);
            lv[j] = f2bf(f - bf2f(hv[j]));
        }
        *reinterpret_cast<u16x4*>(&Xhs[r * XLDS + k4]) = hv;
        *reinterpret_cast<u16x4*>(&Xls[r * XLDS + k4]) = lv;
    }

    // per-block xPos table: 1024 (lr, i) tasks
    for (int p = t; p < 32 * 32; p += 512) {
        const int lr = p >> 5, i = p & 31;
        const int n = (row0 + lr) & (SEQ - 1);
        const float sv = (2.f * (float)i + 25.6f) / 89.6f;
        const float sc = powf(sv, (float)n * (1.f / 512.f));
        const float inv_freq = 1.f / powf(10000.f, (float)i * (1.f / 32.f));
        float sn, cs;
        sincosf((float)n * inv_freq, &sn, &cs);
        float4 o;
        o.x = cs * sc; o.y = sn * sc;   // Q (downscale=False)
        o.z = cs / sc; o.w = sn / sc;   // K (downscale=True)
        Tb[p] = o;
    }
    __syncthreads();

    const int lane = t & 63;
    const int w    = t >> 6;
    const int rt   = w >> 2;    // 0..1 : 16-row tile
    const int ch   = w & 3;     // 0..3 : 3 col-tiles each
    const int frow = rt * 16 + (lane & 15);
    const int fk   = (lane >> 4) * 8;

    f32x4 acc[3];
#pragma unroll
    for (int i = 0; i < 3; ++i) acc[i] = (f32x4)0.f;

#pragma unroll
    for (int kc = 0; kc < 8; ++kc) {
        const bf16x8 ah = *reinterpret_cast<const bf16x8*>(&Xhs[frow * XLDS + kc * 32 + fk]);
        const bf16x8 al = *reinterpret_cast<const bf16x8*>(&Xls[frow * XLDS + kc * 32 + fk]);
#pragma unroll
        for (int ctp = 0; ctp < 3; ++ctp) {
            const int ct = ch * 3 + ctp;
            const size_t fb = (size_t)((ct * 8 + kc) * 64 + lane) * 8;
            const bf16x8 wh = *reinterpret_cast<const bf16x8*>(&Wfh[fb]);
            const bf16x8 wl = *reinterpret_cast<const bf16x8*>(&Wfl[fb]);
            acc[ctp] = __builtin_amdgcn_mfma_f32_16x16x32_bf16(ah, wh, acc[ctp], 0, 0, 0);
            acc[ctp] = __builtin_amdgcn_mfma_f32_16x16x32_bf16(al, wh, acc[ctp], 0, 0, 0);
            acc[ctp] = __builtin_amdgcn_mfma_f32_16x16x32_bf16(ah, wl, acc[ctp], 0, 0, 0);
        }
    }

    // emit: pair adjacent columns (2i,2i+1) -> u32 stores.
    // even lanes handle regs 0-1, odd lanes regs 2-3 (both columns of the pair).
    const int sel   = lane & 1;
    const int c16   = lane & 15;
    const int rbase = (lane >> 4) * 4;

#pragma unroll
    for (int ctp = 0; ctp < 3; ++ctp) {
        const int ct = ch * 3 + ctp;
        float xp[4];
#pragma unroll
        for (int reg = 0; reg < 4; ++reg)
            xp[reg] = __shfl_xor(acc[ctp][reg], 1, 64);
#pragma unroll
        for (int rr = 0; rr < 2; ++rr) {
            const int reg = sel * 2 + rr;
            const float xe = sel ? xp[reg] : acc[ctp][reg];   // even-col value
            const float xo = sel ? acc[ctp][reg] : xp[reg];   // odd-col value
            const int lr = rt * 16 + rbase + reg;             // local row 0..31
            const int r  = row0 + lr;                         // global row
            if (ct < 8) {
                const bool isK = ct >= 4;
                const int cq0 = (ct & 3) * 16 + (c16 & ~1);
                const int i   = cq0 >> 1;
                const float4 tb = Tb[lr * 32 + i];
                const float cs = isK ? tb.z : tb.x;
                const float sn = isK ? tb.w : tb.y;
                const float oe = xe * cs - xo * sn;
                const float oo = xo * cs + xe * sn;
                const u16 he = f2bf(oe), ho = f2bf(oo);
                const u32 hw = (u32)he | ((u32)ho << 16);
                const u32 lw = (u32)f2bf(oe - bf2f(he)) | ((u32)f2bf(oo - bf2f(ho)) << 16);
                u32* Ph = reinterpret_cast<u32*>(isK ? Kh : Qh);
                u32* Pl = reinterpret_cast<u32*>(isK ? Kl : Ql);
                Ph[(r * HD + cq0) >> 1] = hw;
                Pl[(r * HD + cq0) >> 1] = lw;
            } else {
                const int cv0 = (ct - 8) * 16 + (c16 & ~1);
                const u32 w32 = (u32)f2bf(xe) | ((u32)f2bf(xo) << 16);
                reinterpret_cast<u32*>(Vb)[(r * HD + cv0) >> 1] = w32;
            }
        }
    }
}

// ---------------------------------------------------------------------------
// Banded retention. 256 blocks x 1024 thr (16 waves, 4/SIMD).
// Wave (rb,cb) owns the 16x16 S/O tile. K & Q: global->register (no LDS),
// K double-buffer prefetched. V: LDS chunk-XOR transpose, dbuf. S: LDS dbuf.
// ONE barrier per tile.
// ---------------------------------------------------------------------------
#define KRS 72
#define SW  68

__device__ __forceinline__ bf16x8 ld_s8(const u16* p) {
    const u16x4 lo = *reinterpret_cast<const u16x4*>(p);
    const u16x4 hi = *reinterpret_cast<const u16x4*>(p + 4);
    bf16x8 r;
#pragma unroll
    for (int j = 0; j < 4; ++j) { r[j] = (short)lo[j]; r[4 + j] = (short)hi[j]; }
    return r;
}

__global__ __launch_bounds__(1024)
void retention_kernel(const u16* __restrict__ Qh16, const u16* __restrict__ Ql16,
                      const u16* __restrict__ Kh16, const u16* __restrict__ Kl16,
                      const u16* __restrict__ Vb, float* __restrict__ Out)
{
    __shared__ __align__(16) u16 Vts[2][64 * KRS];
    __shared__ __align__(16) u16 Ss [2][64 * SW];

    const int t    = threadIdx.x;
    const int lane = t & 63;
    const int w    = t >> 6;       // 0..15
    const int rb   = w >> 2;       // 0..3 : 16-row strip of S/O
    const int cb   = w & 3;        // 0..3 : 16-col strip

    // XCD swizzle: bijective for 256 blocks / 8 XCDs
    const int flat = blockIdx.x + 64 * blockIdx.y;
    const int work = (flat & 7) * 32 + (flat >> 3);
    const int nt   = work & 63;
    const int b    = work >> 6;
    const int n0   = nt * 64;
    const int bbase = b * SEQ;

    // V staging roles (t < 512)
    const int srow = (t & 511) >> 3;           // 0..63
    const int scol = (t & 7) * 8;
    const int vch  = ((srow >> 3) ^ (t & 7)) & 7;
    const int vidx = vch * 8 + (srow & 7);

    const int mt0 = (nt >= WT) ? (nt - WT) : 0;

    // fragment addressing (global)
    const int frow = rb * 16 + (lane & 15);    // Q/O row
    const int mrow = cb * 16 + (lane & 15);    // K/V row (m)
    const int fk   = (lane >> 4) * 8;

    // Q fragments once, straight from global
    const size_t gq = (size_t)(bbase + n0 + frow) * HD + fk;
    const bf16x8 qh0 = *reinterpret_cast<const bf16x8*>(&Qh16[gq]);
    const bf16x8 qh1 = *reinterpret_cast<const bf16x8*>(&Qh16[gq + 32]);
    const bf16x8 ql0 = *reinterpret_cast<const bf16x8*>(&Ql16[gq]);
    const bf16x8 ql1 = *reinterpret_cast<const bf16x8*>(&Ql16[gq + 32]);

    // K fragment pipeline (cur regs + prefetch)
    size_t gk = (size_t)(bbase + mt0 * 64 + mrow) * HD + fk;
    bf16x8 kh0 = *reinterpret_cast<const bf16x8*>(&Kh16[gk]);
    bf16x8 kh1 = *reinterpret_cast<const bf16x8*>(&Kh16[gk + 32]);
    bf16x8 kl0 = *reinterpret_cast<const bf16x8*>(&Kl16[gk]);
    bf16x8 kl1 = *reinterpret_cast<const bf16x8*>(&Kl16[gk + 32]);

    // V pipeline (t<512): regs for current tile
    u16x8 pv;
    if (t < 512)
        pv = *reinterpret_cast<const u16x8*>(&Vb[(size_t)(bbase + mt0 * 64 + srow) * HD + scol]);

    // decay constants: gamma^d = gamma^(n0-m0) * gamma^(nloc-mloc)
    const float log2g = -0.04580368544f;   // log2(0.96875)
    const int nlocB = rb * 16 + (lane >> 4) * 4;
    const int mloc  = cb * 16 + (lane & 15);
    float gd[4]; int dd[4];
#pragma unroll
    for (int reg = 0; reg < 4; ++reg) {
        dd[reg] = nlocB + reg - mloc;
        gd[reg] = exp2f((float)dd[reg] * log2g);
    }

    f32x4 accO = (f32x4)0.f;
    const int c0 = ((lane >> 4)     ^ (mrow >> 3)) & 7;
    const int c1 = (((lane >> 4) + 4) ^ (mrow >> 3)) & 7;

    for (int mt = mt0; mt <= nt; ++mt) {
        const int cur  = (mt - mt0) & 1;
        const int m0   = mt * 64;
        const bool pref = (mt < nt);

        // 1. prefetch next K (regs) and next V (regs, t<512)
        bf16x8 nkh0, nkh1, nkl0, nkl1; u16x8 nv;
        if (pref) {
            const size_t g = (size_t)(bbase + m0 + 64 + mrow) * HD + fk;
            nkh0 = *reinterpret_cast<const bf16x8*>(&Kh16[g]);
            nkh1 = *reinterpret_cast<const bf16x8*>(&Kh16[g + 32]);
            nkl0 = *reinterpret_cast<const bf16x8*>(&Kl16[g]);
            nkl1 = *reinterpret_cast<const bf16x8*>(&Kl16[g + 32]);
            if (t < 512)
                nv = *reinterpret_cast<const u16x8*>(&Vb[(size_t)(bbase + m0 + 64 + srow) * HD + scol]);
        }

        // 2. S = Q K^T (hi/lo 3-term) from registers
        f32x4 accS = (f32x4)0.f;
        accS = __builtin_amdgcn_mfma_f32_16x16x32_bf16(qh0, kh0, accS, 0, 0, 0);
        accS = __builtin_amdgcn_mfma_f32_16x16x32_bf16(qh1, kh1, accS, 0, 0, 0);
        accS = __builtin_amdgcn_mfma_f32_16x16x32_bf16(ql0, kh0, accS, 0, 0, 0);
        accS = __builtin_amdgcn_mfma_f32_16x16x32_bf16(ql1, kh1, accS, 0, 0, 0);
        accS = __builtin_amdgcn_mfma_f32_16x16x32_bf16(qh0, kl0, accS, 0, 0, 0);
        accS = __builtin_amdgcn_mfma_f32_16x16x32_bf16(qh1, kl1, accS, 0, 0, 0);

        // 3. decay + mask + bf16 -> Ss[cur]
        const float gs = exp2f((float)(n0 - m0) * log2g);
#pragma unroll
        for (int reg = 0; reg < 4; ++reg) {
            const int d   = (n0 - m0) + dd[reg];
            const float g = (d >= 0) ? gs * gd[reg] : 0.f;
            Ss[cur][(nlocB + reg) * SW + mloc] = f2bf(accS[reg] * g);
        }

        // 4. write current V tile -> Vts[cur] (transposed, chunk-XOR)
        if (t < 512) {
#pragma unroll
            for (int j = 0; j < 8; ++j)
                Vts[cur][(scol + j) * KRS + vidx] = pv[j];
        }

        __syncthreads();   // S[cur], V[cur] ready (single barrier per tile)

        // 5. O += S V
        const bf16x8 s0 = ld_s8(&Ss[cur][frow * SW + fk]);
        const bf16x8 s1 = ld_s8(&Ss[cur][frow * SW + 32 + fk]);
        const bf16x8 v0 = *reinterpret_cast<const bf16x8*>(&Vts[cur][mrow * KRS + c0 * 8]);
        const bf16x8 v1 = *reinterpret_cast<const bf16x8*>(&Vts[cur][mrow * KRS + c1 * 8]);
        accO = __builtin_amdgcn_mfma_f32_16x16x32_bf16(s0, v0, accO, 0, 0, 0);
        accO = __builtin_amdgcn_mfma_f32_16x16x32_bf16(s1, v1, accO, 0, 0, 0);

        // 6. roll pipelines
        kh0 = nkh0; kh1 = nkh1; kl0 = nkl0; kl1 = nkl1;
        pv  = nv;
    }

    // write output (fp32)
    const int v = cb * 16 + (lane & 15);
#pragma unroll
    for (int reg = 0; reg < 4; ++reg) {
        const int n = n0 + rb * 16 + (lane >> 4) * 4 + reg;
        Out[(size_t)(bbase + n) * HD + v] = accO[reg];
    }
}

// ---------------------------------------------------------------------------
extern "C" void kernel_launch(void* const* d_in, const int* in_sizes, int n_in,
                              void* d_out, int out_size, void* d_ws, size_t ws_size,
                              hipStream_t stream)
{
    const float* X  = (const float*)d_in[0];
    const float* WQ = (const float*)d_in[1];
    const float* WK = (const float*)d_in[2];
    const float* WV = (const float*)d_in[3];
    float* Out = (float*)d_out;

    char* ws = (char*)d_ws;
    const size_t SZ = (size_t)NB * SEQ * HD * sizeof(u16);   // 2 MB
    u16* Qh = (u16*)(ws);
    u16* Ql = (u16*)(ws + SZ);
    u16* Kh = (u16*)(ws + 2 * SZ);
    u16* Kl = (u16*)(ws + 3 * SZ);
    u16* Vb = (u16*)(ws + 4 * SZ);
    u16* Wfh = (u16*)(ws + 5 * SZ);                          // 96 KB (pad 128K)
    u16* Wfl = (u16*)(ws + 5 * SZ + (128 << 10));

    prep_kernel<<<dim3(24), 256, 0, stream>>>(WQ, WK, WV, Wfh, Wfl);
    proj_kernel<<<dim3(512), 512, 0, stream>>>(
        X, Wfh, Wfl, Qh, Ql, Kh, Kl, Vb);
    retention_kernel<<<dim3(64, NB), 1024, 0, stream>>>(
        Qh, Ql, Kh, Kl, Vb, Out);
}

// Round 7
// 39.423 us; speedup vs baseline: 1.3187x; 1.3187x over previous
//
#include <hip/hip_runtime.h>
#include <hip/hip_bf16.h>
#include <math.h>

// SimpleRetention on MI355X, round 7 (re-anchor at r5 + Q-direct-global).
// out = (Q K^T ∘ D) V, D[n,m]=gamma^(n-m)[n>=m], gamma=0.96875.
// Banded: gamma^513 ~ 8e-8 -> window of 8 previous 64-tiles + diagonal.
// prep: xPos table (512 blocks) + W fragment swizzle (24 blocks).
// proj v4 (r5): X->bf16 hi/lo once to LDS, table from global, hi/lo 3-term MFMA.
// retention v5: r5 structure (K/V LDS dbuf, 2 barriers, stride-72, XCD swizzle)
//               but Q fragments go global->register (no Q LDS; 62.5 KB LDS).

#define SEQ    4096
#define NB     4
#define HID    256
#define HD     64
#define WT     8

typedef short          bf16x8 __attribute__((ext_vector_type(8)));
typedef float          f32x4  __attribute__((ext_vector_type(4)));
typedef unsigned short u16;
typedef unsigned int   u32;
typedef u16            u16x8  __attribute__((ext_vector_type(8)));
typedef u16            u16x4  __attribute__((ext_vector_type(4)));

__device__ __forceinline__ u16 f2bf(float f) {
    __hip_bfloat16 h = __float2bfloat16(f);
    return __builtin_bit_cast(u16, h);
}
__device__ __forceinline__ float bf2f(u16 b) {
    __hip_bfloat16 h = __builtin_bit_cast(__hip_bfloat16, b);
    return __bfloat162float(h);
}

// ---------------------------------------------------------------------------
// Prep: xPos table (blocks 0..511) + W fragment swizzle hi/lo (blocks 512..535).
// Wf frag f = ((ct*8 + kc)*64 + lane): b[j] = W[kc*32+(lane>>4)*8+j][ct*16+(lane&15)]
// ---------------------------------------------------------------------------
__global__ __launch_bounds__(256)
void prep_kernel(const float* __restrict__ WQ, const float* __restrict__ WK,
                 const float* __restrict__ WV, float* __restrict__ Tbl,
                 u16* __restrict__ Wfh, u16* __restrict__ Wfl)
{
    const int t = threadIdx.x;
    if (blockIdx.x < 512) {
        const int p = blockIdx.x * 256 + t;
        const int n = p >> 5, i = p & 31;
        const float sv = (2.f * (float)i + 25.6f) / 89.6f;
        const float sc = powf(sv, (float)n * (1.f / 512.f));
        const float inv_freq = 1.f / powf(10000.f, (float)i * (1.f / 32.f));
        float sn, cs;
        sincosf((float)n * inv_freq, &sn, &cs);
        float4 o;
        o.x = cs * sc; o.y = sn * sc;   // Q (downscale=False)
        o.z = cs / sc; o.w = sn / sc;   // K (downscale=True)
        reinterpret_cast<float4*>(Tbl)[p] = o;
    } else {
        const int p = (blockIdx.x - 512) * 256 + t;   // 0..6143
        const int lane = p & 63;
        const int kc   = (p >> 6) & 7;
        const int ct   = p >> 9;                      // 0..11
        const int col  = ct * 16 + (lane & 15);
        const float* Wsrc = (col < 64) ? WQ : (col < 128) ? WK : WV;
        const int c = col & 63;
        u16x8 hv, lv;
#pragma unroll
        for (int j = 0; j < 8; ++j) {
            const float w = Wsrc[(kc * 32 + (lane >> 4) * 8 + j) * HD + c];
            hv[j] = f2bf(w);
            lv[j] = f2bf(w - bf2f(hv[j]));
        }
        *reinterpret_cast<u16x8*>(&Wfh[(size_t)p * 8]) = hv;
        *reinterpret_cast<u16x8*>(&Wfl[(size_t)p * 8]) = lv;
    }
}

// ---------------------------------------------------------------------------
// Projection + fused xPos. 512 blocks x 512 thr, 32 rows/block.
// X converted to hi/lo bf16 once into LDS; waves read b128 A-frags.
// ---------------------------------------------------------------------------
#define XLDS 264   // u16 row stride: 16B-aligned, 2-way bank alias (free)

__global__ __launch_bounds__(512, 4)
void proj_kernel(const float* __restrict__ X, const float* __restrict__ Tbl,
                 const u16* __restrict__ Wfh, const u16* __restrict__ Wfl,
                 u16* __restrict__ Qh, u16* __restrict__ Ql,
                 u16* __restrict__ Kh, u16* __restrict__ Kl,
                 u16* __restrict__ Vb)
{
    __shared__ __align__(16) u16 Xhs[32 * XLDS];
    __shared__ __align__(16) u16 Xls[32 * XLDS];
    const int t = threadIdx.x;
    const int row0 = blockIdx.x * 32;

    // stage X tile as bf16 hi/lo (convert once per block)
    for (int e = t; e < 32 * 64; e += 512) {
        const int r = e >> 6, k4 = (e & 63) << 2;
        const float4 xv = *reinterpret_cast<const float4*>(&X[(size_t)(row0 + r) * HID + k4]);
        u16x4 hv, lv;
#pragma unroll
        for (int j = 0; j < 4; ++j) {
            const float f = (&xv.x)[j];
            hv[j] = f2bf(f);
            lv[j] = f2bf(f - bf2f(hv[j]));
        }
        *reinterpret_cast<u16x4*>(&Xhs[r * XLDS + k4]) = hv;
        *reinterpret_cast<u16x4*>(&Xls[r * XLDS + k4]) = lv;
    }
    __syncthreads();

    const int lane = t & 63;
    const int w    = t >> 6;
    const int rt   = w >> 2;    // 0..1 : 16-row tile
    const int ch   = w & 3;     // 0..3 : 3 col-tiles each
    const int frow = rt * 16 + (lane & 15);
    const int fk   = (lane >> 4) * 8;

    f32x4 acc[3];
#pragma unroll
    for (int i = 0; i < 3; ++i) acc[i] = (f32x4)0.f;

#pragma unroll
    for (int kc = 0; kc < 8; ++kc) {
        const bf16x8 ah = *reinterpret_cast<const bf16x8*>(&Xhs[frow * XLDS + kc * 32 + fk]);
        const bf16x8 al = *reinterpret_cast<const bf16x8*>(&Xls[frow * XLDS + kc * 32 + fk]);
#pragma unroll
        for (int ctp = 0; ctp < 3; ++ctp) {
            const int ct = ch * 3 + ctp;
            const size_t fb = (size_t)((ct * 8 + kc) * 64 + lane) * 8;
            const bf16x8 wh = *reinterpret_cast<const bf16x8*>(&Wfh[fb]);
            const bf16x8 wl = *reinterpret_cast<const bf16x8*>(&Wfl[fb]);
            acc[ctp] = __builtin_amdgcn_mfma_f32_16x16x32_bf16(ah, wh, acc[ctp], 0, 0, 0);
            acc[ctp] = __builtin_amdgcn_mfma_f32_16x16x32_bf16(al, wh, acc[ctp], 0, 0, 0);
            acc[ctp] = __builtin_amdgcn_mfma_f32_16x16x32_bf16(ah, wl, acc[ctp], 0, 0, 0);
        }
    }

    // emit: pair adjacent columns (2i,2i+1) -> u32 stores.
    // even lanes handle regs 0-1, odd lanes regs 2-3 (both columns of the pair).
    const int sel   = lane & 1;
    const int c16   = lane & 15;
    const int rbase = (lane >> 4) * 4;

#pragma unroll
    for (int ctp = 0; ctp < 3; ++ctp) {
        const int ct = ch * 3 + ctp;
        float xp[4];
#pragma unroll
        for (int reg = 0; reg < 4; ++reg)
            xp[reg] = __shfl_xor(acc[ctp][reg], 1, 64);
#pragma unroll
        for (int rr = 0; rr < 2; ++rr) {
            const int reg = sel * 2 + rr;
            const float xe = sel ? xp[reg] : acc[ctp][reg];   // even-col value
            const float xo = sel ? acc[ctp][reg] : xp[reg];   // odd-col value
            const int r = row0 + rt * 16 + rbase + reg;
            if (ct < 8) {
                const bool isK = ct >= 4;
                const int cq0 = (ct & 3) * 16 + (c16 & ~1);
                const int i   = cq0 >> 1;
                const int n   = r & (SEQ - 1);
                const float4 tb = reinterpret_cast<const float4*>(Tbl)[n * 32 + i];
                const float cs = isK ? tb.z : tb.x;
                const float sn = isK ? tb.w : tb.y;
                const float oe = xe * cs - xo * sn;
                const float oo = xo * cs + xe * sn;
                const u16 he = f2bf(oe), ho = f2bf(oo);
                const u32 hw = (u32)he | ((u32)ho << 16);
                const u32 lw = (u32)f2bf(oe - bf2f(he)) | ((u32)f2bf(oo - bf2f(ho)) << 16);
                u32* Ph = reinterpret_cast<u32*>(isK ? Kh : Qh);
                u32* Pl = reinterpret_cast<u32*>(isK ? Kl : Ql);
                Ph[(r * HD + cq0) >> 1] = hw;
                Pl[(r * HD + cq0) >> 1] = lw;
            } else {
                const int cv0 = (ct - 8) * 16 + (c16 & ~1);
                const u32 w32 = (u32)f2bf(xe) | ((u32)f2bf(xo) << 16);
                reinterpret_cast<u32*>(Vb)[(r * HD + cv0) >> 1] = w32;
            }
        }
    }
}

// ---------------------------------------------------------------------------
// Banded retention. 256 blocks x 1024 thr. Wave (rb,cb) owns a 16x16 tile.
// Q frags: global->register (prologue, no LDS). K: LDS dbuf (stride 72).
// V: LDS chunk-XOR transpose dbuf. S: LDS stride 68. 2 barriers per tile.
// LDS total 62.5 KB.
// ---------------------------------------------------------------------------
#define KRS 72
#define SW  68

__device__ __forceinline__ bf16x8 ld_s8(const u16* p) {
    const u16x4 lo = *reinterpret_cast<const u16x4*>(p);
    const u16x4 hi = *reinterpret_cast<const u16x4*>(p + 4);
    bf16x8 r;
#pragma unroll
    for (int j = 0; j < 4; ++j) { r[j] = (short)lo[j]; r[4 + j] = (short)hi[j]; }
    return r;
}

__global__ __launch_bounds__(1024)
void retention_kernel(const u16* __restrict__ Qh16, const u16* __restrict__ Ql16,
                      const u16* __restrict__ Kh16, const u16* __restrict__ Kl16,
                      const u16* __restrict__ Vb, float* __restrict__ Out)
{
    __shared__ __align__(16) u16 Khs[2][64 * KRS];
    __shared__ __align__(16) u16 Kls[2][64 * KRS];
    __shared__ __align__(16) u16 Vts[2][64 * KRS];
    __shared__ __align__(16) u16 Ss [64 * SW];

    const int t    = threadIdx.x;
    const int lane = t & 63;
    const int w    = t >> 6;       // 0..15
    const int rb   = w >> 2;       // 0..3 : 16-row strip of S/O
    const int cb   = w & 3;        // 0..3 : 16-col strip

    // XCD swizzle: bijective for 256 blocks / 8 XCDs
    const int flat = blockIdx.x + 64 * blockIdx.y;
    const int work = (flat & 7) * 32 + (flat >> 3);
    const int nt   = work & 63;
    const int b    = work >> 6;
    const int n0   = nt * 64;
    const int bbase = b * SEQ;

    // staging roles: half 0 -> K hi/lo; half 1 -> V
    const int half = t >> 9;
    const int th   = t & 511;
    const int srow = th >> 3;           // 0..63
    const int scol = (th & 7) * 8;
    const int vch  = ((srow >> 3) ^ (th & 7)) & 7;   // (m>>3) ^ (v>>3)
    const int vidx = vch * 8 + (srow & 7);

    const int mt0 = (nt >= WT) ? (nt - WT) : 0;

    // ---- prologue: stage first K/V tile; Q frags straight from global ----
    {
        const int gk = (bbase + mt0 * 64 + srow) * HD + scol;
        if (half == 0) {
            *reinterpret_cast<u16x8*>(&Khs[0][srow * KRS + scol]) =
                *reinterpret_cast<const u16x8*>(&Kh16[gk]);
            *reinterpret_cast<u16x8*>(&Kls[0][srow * KRS + scol]) =
                *reinterpret_cast<const u16x8*>(&Kl16[gk]);
        } else {
            const u16x8 vv = *reinterpret_cast<const u16x8*>(&Vb[gk]);
#pragma unroll
            for (int j = 0; j < 8; ++j)
                Vts[0][(scol + j) * KRS + vidx] = vv[j];
        }
    }

    const int frow = rb * 16 + (lane & 15);
    const int fk   = (lane >> 4) * 8;
    const size_t gq = (size_t)(bbase + n0 + frow) * HD + fk;
    const bf16x8 qh0 = *reinterpret_cast<const bf16x8*>(&Qh16[gq]);
    const bf16x8 qh1 = *reinterpret_cast<const bf16x8*>(&Qh16[gq + 32]);
    const bf16x8 ql0 = *reinterpret_cast<const bf16x8*>(&Ql16[gq]);
    const bf16x8 ql1 = *reinterpret_cast<const bf16x8*>(&Ql16[gq + 32]);
    __syncthreads();

    // per-lane decay constants: gamma^d = gamma^(n0-m0) * gamma^(nloc-mloc)
    const float log2g = -0.04580368544f;   // log2(0.96875)
    const int nlocB = rb * 16 + (lane >> 4) * 4;
    const int mloc  = cb * 16 + (lane & 15);
    float gd[4]; int dd[4];
#pragma unroll
    for (int reg = 0; reg < 4; ++reg) {
        dd[reg] = nlocB + reg - mloc;
        gd[reg] = exp2f((float)dd[reg] * log2g);
    }

    f32x4 accO = (f32x4)0.f;
    const int mrow = cb * 16 + (lane & 15);
    const int c0 = ((lane >> 4)     ^ (mrow >> 3)) & 7;
    const int c1 = (((lane >> 4) + 4) ^ (mrow >> 3)) & 7;

    for (int mt = mt0; mt <= nt; ++mt) {
        const int cur  = (mt - mt0) & 1;
        const int m0   = mt * 64;
        const bool pref = (mt < nt);

        // 1. issue next-tile global loads (in flight under QK^T)
        u16x8 pk_h, pk_l, pv;
        if (pref) {
            const int gk = (bbase + m0 + 64 + srow) * HD + scol;
            if (half == 0) {
                pk_h = *reinterpret_cast<const u16x8*>(&Kh16[gk]);
                pk_l = *reinterpret_cast<const u16x8*>(&Kl16[gk]);
            } else {
                pv = *reinterpret_cast<const u16x8*>(&Vb[gk]);
            }
        }

        // 2. S = Q K^T (hi/lo 3-term), 16x16 per wave
        const bf16x8 kh0 = *reinterpret_cast<const bf16x8*>(&Khs[cur][mrow * KRS + fk]);
        const bf16x8 kh1 = *reinterpret_cast<const bf16x8*>(&Khs[cur][mrow * KRS + 32 + fk]);
        const bf16x8 kl0 = *reinterpret_cast<const bf16x8*>(&Kls[cur][mrow * KRS + fk]);
        const bf16x8 kl1 = *reinterpret_cast<const bf16x8*>(&Kls[cur][mrow * KRS + 32 + fk]);
        f32x4 accS = (f32x4)0.f;
        accS = __builtin_amdgcn_mfma_f32_16x16x32_bf16(qh0, kh0, accS, 0, 0, 0);
        accS = __builtin_amdgcn_mfma_f32_16x16x32_bf16(qh1, kh1, accS, 0, 0, 0);
        accS = __builtin_amdgcn_mfma_f32_16x16x32_bf16(ql0, kh0, accS, 0, 0, 0);
        accS = __builtin_amdgcn_mfma_f32_16x16x32_bf16(ql1, kh1, accS, 0, 0, 0);
        accS = __builtin_amdgcn_mfma_f32_16x16x32_bf16(qh0, kl0, accS, 0, 0, 0);
        accS = __builtin_amdgcn_mfma_f32_16x16x32_bf16(qh1, kl1, accS, 0, 0, 0);

        // 3. decay + mask + bf16 -> Ss
        const float gs = exp2f((float)(n0 - m0) * log2g);
#pragma unroll
        for (int reg = 0; reg < 4; ++reg) {
            const int d   = (n0 - m0) + dd[reg];
            const float g = (d >= 0) ? gs * gd[reg] : 0.f;
            Ss[(nlocB + reg) * SW + mloc] = f2bf(accS[reg] * g);
        }

        // 4. write prefetched K/V -> buf[cur^1]
        if (pref) {
            if (half == 0) {
                *reinterpret_cast<u16x8*>(&Khs[cur ^ 1][srow * KRS + scol]) = pk_h;
                *reinterpret_cast<u16x8*>(&Kls[cur ^ 1][srow * KRS + scol]) = pk_l;
            } else {
#pragma unroll
                for (int j = 0; j < 8; ++j)
                    Vts[cur ^ 1][(scol + j) * KRS + vidx] = pv[j];
            }
        }

        __syncthreads();   // B1: Ss ready; next K/V staged

        // 5. O += S V
        const bf16x8 s0 = ld_s8(&Ss[frow * SW + fk]);
        const bf16x8 s1 = ld_s8(&Ss[frow * SW + 32 + fk]);
        const bf16x8 v0 = *reinterpret_cast<const bf16x8*>(&Vts[cur][mrow * KRS + c0 * 8]);
        const bf16x8 v1 = *reinterpret_cast<const bf16x8*>(&Vts[cur][mrow * KRS + c1 * 8]);
        accO = __builtin_amdgcn_mfma_f32_16x16x32_bf16(s0, v0, accO, 0, 0, 0);
        accO = __builtin_amdgcn_mfma_f32_16x16x32_bf16(s1, v1, accO, 0, 0, 0);

        __syncthreads();   // B2: SV reads done -> Ss/Vts reusable
    }

    // write output (fp32)
    const int v = cb * 16 + (lane & 15);
#pragma unroll
    for (int reg = 0; reg < 4; ++reg) {
        const int n = n0 + rb * 16 + (lane >> 4) * 4 + reg;
        Out[(size_t)(bbase + n) * HD + v] = accO[reg];
    }
}

// ---------------------------------------------------------------------------
extern "C" void kernel_launch(void* const* d_in, const int* in_sizes, int n_in,
                              void* d_out, int out_size, void* d_ws, size_t ws_size,
                              hipStream_t stream)
{
    const float* X  = (const float*)d_in[0];
    const float* WQ = (const float*)d_in[1];
    const float* WK = (const float*)d_in[2];
    const float* WV = (const float*)d_in[3];
    float* Out = (float*)d_out;

    char* ws = (char*)d_ws;
    const size_t SZ = (size_t)NB * SEQ * HD * sizeof(u16);   // 2 MB
    u16* Qh = (u16*)(ws);
    u16* Ql = (u16*)(ws + SZ);
    u16* Kh = (u16*)(ws + 2 * SZ);
    u16* Kl = (u16*)(ws + 3 * SZ);
    u16* Vb = (u16*)(ws + 4 * SZ);
    float* Tbl = (float*)(ws + 5 * SZ);                      // 2 MB
    u16* Wfh = (u16*)(ws + 6 * SZ);                          // 96 KB (pad 128K)
    u16* Wfl = (u16*)(ws + 6 * SZ + (128 << 10));

    prep_kernel<<<dim3(536), 256, 0, stream>>>(WQ, WK, WV, Tbl, Wfh, Wfl);
    proj_kernel<<<dim3(512), 512, 0, stream>>>(
        X, Tbl, Wfh, Wfl, Qh, Ql, Kh, Kl, Vb);
    retention_kernel<<<dim3(64, NB), 1024, 0, stream>>>(
        Qh, Ql, Kh, Kl, Vb, Out);
}

// Round 8
// 36.072 us; speedup vs baseline: 1.4412x; 1.0929x over previous
//
#include <hip/hip_runtime.h>
#include <hip/hip_bf16.h>
#include <math.h>

// SimpleRetention on MI355X, round 8.
// out = (Q K^T ∘ D) V, D[n,m]=gamma^(n-m)[n>=m], gamma=0.96875.
// Banded: gamma^513 ~ 8e-8 -> window of 8 previous 64-tiles + diagonal.
// proj v6: 64 rows/block (halved W L2 traffic), X hi/lo 3-term MFMA (needed:
//          sqrt(256) cancellation), Q/K emitted as PLAIN bf16 (QK^T only
//          amplifies sqrt(64) -> bf16 Q/K adds ~5e-5 absmax, fine).
// retention v6: r7 structure, single-K (2-MFMA QK^T), 44.7 KB LDS.

#define SEQ    4096
#define NB     4
#define HID    256
#define HD     64
#define WT     8

typedef short          bf16x8 __attribute__((ext_vector_type(8)));
typedef float          f32x4  __attribute__((ext_vector_type(4)));
typedef unsigned short u16;
typedef unsigned int   u32;
typedef u16            u16x8  __attribute__((ext_vector_type(8)));
typedef u16            u16x4  __attribute__((ext_vector_type(4)));

__device__ __forceinline__ u16 f2bf(float f) {
    __hip_bfloat16 h = __float2bfloat16(f);
    return __builtin_bit_cast(u16, h);
}
__device__ __forceinline__ float bf2f(u16 b) {
    __hip_bfloat16 h = __builtin_bit_cast(__hip_bfloat16, b);
    return __bfloat162float(h);
}

// ---------------------------------------------------------------------------
// Prep: xPos table (blocks 0..511) + W fragment swizzle hi/lo (blocks 512..535).
// Wf frag f = ((ct*8 + kc)*64 + lane): b[j] = W[kc*32+(lane>>4)*8+j][ct*16+(lane&15)]
// ---------------------------------------------------------------------------
__global__ __launch_bounds__(256)
void prep_kernel(const float* __restrict__ WQ, const float* __restrict__ WK,
                 const float* __restrict__ WV, float* __restrict__ Tbl,
                 u16* __restrict__ Wfh, u16* __restrict__ Wfl)
{
    const int t = threadIdx.x;
    if (blockIdx.x < 512) {
        const int p = blockIdx.x * 256 + t;
        const int n = p >> 5, i = p & 31;
        const float sv = (2.f * (float)i + 25.6f) / 89.6f;
        const float sc = powf(sv, (float)n * (1.f / 512.f));
        const float inv_freq = 1.f / powf(10000.f, (float)i * (1.f / 32.f));
        float sn, cs;
        sincosf((float)n * inv_freq, &sn, &cs);
        float4 o;
        o.x = cs * sc; o.y = sn * sc;   // Q (downscale=False)
        o.z = cs / sc; o.w = sn / sc;   // K (downscale=True)
        reinterpret_cast<float4*>(Tbl)[p] = o;
    } else {
        const int p = (blockIdx.x - 512) * 256 + t;   // 0..6143
        const int lane = p & 63;
        const int kc   = (p >> 6) & 7;
        const int ct   = p >> 9;                      // 0..11
        const int col  = ct * 16 + (lane & 15);
        const float* Wsrc = (col < 64) ? WQ : (col < 128) ? WK : WV;
        const int c = col & 63;
        u16x8 hv, lv;
#pragma unroll
        for (int j = 0; j < 8; ++j) {
            const float w = Wsrc[(kc * 32 + (lane >> 4) * 8 + j) * HD + c];
            hv[j] = f2bf(w);
            lv[j] = f2bf(w - bf2f(hv[j]));
        }
        *reinterpret_cast<u16x8*>(&Wfh[(size_t)p * 8]) = hv;
        *reinterpret_cast<u16x8*>(&Wfl[(size_t)p * 8]) = lv;
    }
}

// ---------------------------------------------------------------------------
// Projection + fused xPos. 256 blocks x 512 thr, 64 rows/block.
// X converted to hi/lo bf16 once into LDS; each wave: 2 row-tiles x 3 col-tiles.
// Q/K/V emitted as plain bf16.
// ---------------------------------------------------------------------------
#define XLDS 264   // u16 row stride: 16B-aligned, 2-way bank alias (free)

__global__ __launch_bounds__(512, 4)
void proj_kernel(const float* __restrict__ X, const float* __restrict__ Tbl,
                 const u16* __restrict__ Wfh, const u16* __restrict__ Wfl,
                 u16* __restrict__ Qb, u16* __restrict__ Kb, u16* __restrict__ Vb)
{
    __shared__ __align__(16) u16 Xhs[64 * XLDS];
    __shared__ __align__(16) u16 Xls[64 * XLDS];
    const int t = threadIdx.x;
    const int row0 = blockIdx.x * 64;

    // stage X tile as bf16 hi/lo (convert once per block)
    for (int e = t; e < 64 * 64; e += 512) {
        const int r = e >> 6, k4 = (e & 63) << 2;
        const float4 xv = *reinterpret_cast<const float4*>(&X[(size_t)(row0 + r) * HID + k4]);
        u16x4 hv, lv;
#pragma unroll
        for (int j = 0; j < 4; ++j) {
            const float f = (&xv.x)[j];
            hv[j] = f2bf(f);
            lv[j] = f2bf(f - bf2f(hv[j]));
        }
        *reinterpret_cast<u16x4*>(&Xhs[r * XLDS + k4]) = hv;
        *reinterpret_cast<u16x4*>(&Xls[r * XLDS + k4]) = lv;
    }
    __syncthreads();

    const int lane = t & 63;
    const int w    = t >> 6;
    const int rt2  = w >> 2;    // 0..1 : 32-row half
    const int ch   = w & 3;     // 0..3 : 3 col-tiles each
    const int fk   = (lane >> 4) * 8;
    const int fra  = rt2 * 32 + (lane & 15);   // row-tile 0 row
    const int frb  = fra + 16;                 // row-tile 1 row

    f32x4 acc[2][3];
#pragma unroll
    for (int a = 0; a < 2; ++a)
#pragma unroll
        for (int c = 0; c < 3; ++c) acc[a][c] = (f32x4)0.f;

#pragma unroll
    for (int kc = 0; kc < 8; ++kc) {
        const bf16x8 aha = *reinterpret_cast<const bf16x8*>(&Xhs[fra * XLDS + kc * 32 + fk]);
        const bf16x8 ala = *reinterpret_cast<const bf16x8*>(&Xls[fra * XLDS + kc * 32 + fk]);
        const bf16x8 ahb = *reinterpret_cast<const bf16x8*>(&Xhs[frb * XLDS + kc * 32 + fk]);
        const bf16x8 alb = *reinterpret_cast<const bf16x8*>(&Xls[frb * XLDS + kc * 32 + fk]);
#pragma unroll
        for (int ctp = 0; ctp < 3; ++ctp) {
            const int ct = ch * 3 + ctp;
            const size_t fb = (size_t)((ct * 8 + kc) * 64 + lane) * 8;
            const bf16x8 wh = *reinterpret_cast<const bf16x8*>(&Wfh[fb]);
            const bf16x8 wl = *reinterpret_cast<const bf16x8*>(&Wfl[fb]);
            acc[0][ctp] = __builtin_amdgcn_mfma_f32_16x16x32_bf16(aha, wh, acc[0][ctp], 0, 0, 0);
            acc[1][ctp] = __builtin_amdgcn_mfma_f32_16x16x32_bf16(ahb, wh, acc[1][ctp], 0, 0, 0);
            acc[0][ctp] = __builtin_amdgcn_mfma_f32_16x16x32_bf16(ala, wh, acc[0][ctp], 0, 0, 0);
            acc[1][ctp] = __builtin_amdgcn_mfma_f32_16x16x32_bf16(alb, wh, acc[1][ctp], 0, 0, 0);
            acc[0][ctp] = __builtin_amdgcn_mfma_f32_16x16x32_bf16(aha, wl, acc[0][ctp], 0, 0, 0);
            acc[1][ctp] = __builtin_amdgcn_mfma_f32_16x16x32_bf16(ahb, wl, acc[1][ctp], 0, 0, 0);
        }
    }

    // emit: pair adjacent columns (2i,2i+1) -> u32 stores (plain bf16).
    // even lanes handle regs 0-1, odd lanes regs 2-3 (both columns of the pair).
    const int sel   = lane & 1;
    const int c16   = lane & 15;
    const int rbase = (lane >> 4) * 4;

#pragma unroll
    for (int rt = 0; rt < 2; ++rt) {
#pragma unroll
        for (int ctp = 0; ctp < 3; ++ctp) {
            const int ct = ch * 3 + ctp;
            float xp[4];
#pragma unroll
            for (int reg = 0; reg < 4; ++reg)
                xp[reg] = __shfl_xor(acc[rt][ctp][reg], 1, 64);
#pragma unroll
            for (int rr = 0; rr < 2; ++rr) {
                const int reg = sel * 2 + rr;
                const float xe = sel ? xp[reg] : acc[rt][ctp][reg];   // even-col value
                const float xo = sel ? acc[rt][ctp][reg] : xp[reg];   // odd-col value
                const int r = row0 + rt2 * 32 + rt * 16 + rbase + reg;
                if (ct < 8) {
                    const bool isK = ct >= 4;
                    const int cq0 = (ct & 3) * 16 + (c16 & ~1);
                    const int i   = cq0 >> 1;
                    const int n   = r & (SEQ - 1);
                    const float4 tb = reinterpret_cast<const float4*>(Tbl)[n * 32 + i];
                    const float cs = isK ? tb.z : tb.x;
                    const float sn = isK ? tb.w : tb.y;
                    const float oe = xe * cs - xo * sn;
                    const float oo = xo * cs + xe * sn;
                    const u32 hw = (u32)f2bf(oe) | ((u32)f2bf(oo) << 16);
                    u32* P = reinterpret_cast<u32*>(isK ? Kb : Qb);
                    P[(r * HD + cq0) >> 1] = hw;
                } else {
                    const int cv0 = (ct - 8) * 16 + (c16 & ~1);
                    const u32 w32 = (u32)f2bf(xe) | ((u32)f2bf(xo) << 16);
                    reinterpret_cast<u32*>(Vb)[(r * HD + cv0) >> 1] = w32;
                }
            }
        }
    }
}

// ---------------------------------------------------------------------------
// Banded retention. 256 blocks x 1024 thr. Wave (rb,cb) owns a 16x16 tile.
// Q frags: global->register. K: LDS dbuf (stride 72, plain bf16, 2-MFMA QK^T).
// V: LDS chunk-XOR transpose dbuf. S: LDS stride 68. 2 barriers per tile.
// LDS 44.7 KB.
// ---------------------------------------------------------------------------
#define KRS 72
#define SW  68

__device__ __forceinline__ bf16x8 ld_s8(const u16* p) {
    const u16x4 lo = *reinterpret_cast<const u16x4*>(p);
    const u16x4 hi = *reinterpret_cast<const u16x4*>(p + 4);
    bf16x8 r;
#pragma unroll
    for (int j = 0; j < 4; ++j) { r[j] = (short)lo[j]; r[4 + j] = (short)hi[j]; }
    return r;
}

__global__ __launch_bounds__(1024)
void retention_kernel(const u16* __restrict__ Qb, const u16* __restrict__ Kb,
                      const u16* __restrict__ Vb, float* __restrict__ Out)
{
    __shared__ __align__(16) u16 Khs[2][64 * KRS];
    __shared__ __align__(16) u16 Vts[2][64 * KRS];
    __shared__ __align__(16) u16 Ss [64 * SW];

    const int t    = threadIdx.x;
    const int lane = t & 63;
    const int w    = t >> 6;       // 0..15
    const int rb   = w >> 2;       // 0..3 : 16-row strip of S/O
    const int cb   = w & 3;        // 0..3 : 16-col strip

    // XCD swizzle: bijective for 256 blocks / 8 XCDs
    const int flat = blockIdx.x + 64 * blockIdx.y;
    const int work = (flat & 7) * 32 + (flat >> 3);
    const int nt   = work & 63;
    const int b    = work >> 6;
    const int n0   = nt * 64;
    const int bbase = b * SEQ;

    // staging roles: half 0 -> K; half 1 -> V (each 512 thr, one b128 per tile)
    const int half = t >> 9;
    const int th   = t & 511;
    const int srow = th >> 3;           // 0..63
    const int scol = (th & 7) * 8;
    const int vch  = ((srow >> 3) ^ (th & 7)) & 7;   // (m>>3) ^ (v>>3)
    const int vidx = vch * 8 + (srow & 7);

    const int mt0 = (nt >= WT) ? (nt - WT) : 0;

    // ---- prologue: stage first K/V tile; Q frags straight from global ----
    {
        const int gk = (bbase + mt0 * 64 + srow) * HD + scol;
        if (half == 0) {
            *reinterpret_cast<u16x8*>(&Khs[0][srow * KRS + scol]) =
                *reinterpret_cast<const u16x8*>(&Kb[gk]);
        } else {
            const u16x8 vv = *reinterpret_cast<const u16x8*>(&Vb[gk]);
#pragma unroll
            for (int j = 0; j < 8; ++j)
                Vts[0][(scol + j) * KRS + vidx] = vv[j];
        }
    }

    const int frow = rb * 16 + (lane & 15);
    const int fk   = (lane >> 4) * 8;
    const size_t gq = (size_t)(bbase + n0 + frow) * HD + fk;
    const bf16x8 qb0 = *reinterpret_cast<const bf16x8*>(&Qb[gq]);
    const bf16x8 qb1 = *reinterpret_cast<const bf16x8*>(&Qb[gq + 32]);
    __syncthreads();

    // per-lane decay constants: gamma^d = gamma^(n0-m0) * gamma^(nloc-mloc)
    const float log2g = -0.04580368544f;   // log2(0.96875)
    const int nlocB = rb * 16 + (lane >> 4) * 4;
    const int mloc  = cb * 16 + (lane & 15);
    float gd[4]; int dd[4];
#pragma unroll
    for (int reg = 0; reg < 4; ++reg) {
        dd[reg] = nlocB + reg - mloc;
        gd[reg] = exp2f((float)dd[reg] * log2g);
    }

    f32x4 accO = (f32x4)0.f;
    const int mrow = cb * 16 + (lane & 15);
    const int c0 = ((lane >> 4)     ^ (mrow >> 3)) & 7;
    const int c1 = (((lane >> 4) + 4) ^ (mrow >> 3)) & 7;

    for (int mt = mt0; mt <= nt; ++mt) {
        const int cur  = (mt - mt0) & 1;
        const int m0   = mt * 64;
        const bool pref = (mt < nt);

        // 1. issue next-tile global loads (in flight under QK^T)
        u16x8 pk, pv;
        if (pref) {
            const int gk = (bbase + m0 + 64 + srow) * HD + scol;
            if (half == 0) pk = *reinterpret_cast<const u16x8*>(&Kb[gk]);
            else           pv = *reinterpret_cast<const u16x8*>(&Vb[gk]);
        }

        // 2. S = Q K^T (plain bf16, 2 MFMA), 16x16 per wave
        const bf16x8 kb0 = *reinterpret_cast<const bf16x8*>(&Khs[cur][mrow * KRS + fk]);
        const bf16x8 kb1 = *reinterpret_cast<const bf16x8*>(&Khs[cur][mrow * KRS + 32 + fk]);
        f32x4 accS = (f32x4)0.f;
        accS = __builtin_amdgcn_mfma_f32_16x16x32_bf16(qb0, kb0, accS, 0, 0, 0);
        accS = __builtin_amdgcn_mfma_f32_16x16x32_bf16(qb1, kb1, accS, 0, 0, 0);

        // 3. decay + mask + bf16 -> Ss
        const float gs = exp2f((float)(n0 - m0) * log2g);
#pragma unroll
        for (int reg = 0; reg < 4; ++reg) {
            const int d   = (n0 - m0) + dd[reg];
            const float g = (d >= 0) ? gs * gd[reg] : 0.f;
            Ss[(nlocB + reg) * SW + mloc] = f2bf(accS[reg] * g);
        }

        // 4. write prefetched K/V -> buf[cur^1]
        if (pref) {
            if (half == 0) {
                *reinterpret_cast<u16x8*>(&Khs[cur ^ 1][srow * KRS + scol]) = pk;
            } else {
#pragma unroll
                for (int j = 0; j < 8; ++j)
                    Vts[cur ^ 1][(scol + j) * KRS + vidx] = pv[j];
            }
        }

        __syncthreads();   // B1: Ss ready; next K/V staged

        // 5. O += S V
        const bf16x8 s0 = ld_s8(&Ss[frow * SW + fk]);
        const bf16x8 s1 = ld_s8(&Ss[frow * SW + 32 + fk]);
        const bf16x8 v0 = *reinterpret_cast<const bf16x8*>(&Vts[cur][mrow * KRS + c0 * 8]);
        const bf16x8 v1 = *reinterpret_cast<const bf16x8*>(&Vts[cur][mrow * KRS + c1 * 8]);
        accO = __builtin_amdgcn_mfma_f32_16x16x32_bf16(s0, v0, accO, 0, 0, 0);
        accO = __builtin_amdgcn_mfma_f32_16x16x32_bf16(s1, v1, accO, 0, 0, 0);

        __syncthreads();   // B2: SV reads done -> Ss/Vts reusable
    }

    // write output (fp32)
    const int v = cb * 16 + (lane & 15);
#pragma unroll
    for (int reg = 0; reg < 4; ++reg) {
        const int n = n0 + rb * 16 + (lane >> 4) * 4 + reg;
        Out[(size_t)(bbase + n) * HD + v] = accO[reg];
    }
}

// ---------------------------------------------------------------------------
extern "C" void kernel_launch(void* const* d_in, const int* in_sizes, int n_in,
                              void* d_out, int out_size, void* d_ws, size_t ws_size,
                              hipStream_t stream)
{
    const float* X  = (const float*)d_in[0];
    const float* WQ = (const float*)d_in[1];
    const float* WK = (const float*)d_in[2];
    const float* WV = (const float*)d_in[3];
    float* Out = (float*)d_out;

    char* ws = (char*)d_ws;
    const size_t SZ = (size_t)NB * SEQ * HD * sizeof(u16);   // 2 MB
    u16* Qb = (u16*)(ws);
    u16* Kb = (u16*)(ws + SZ);
    u16* Vb = (u16*)(ws + 2 * SZ);
    float* Tbl = (float*)(ws + 3 * SZ);                      // 2 MB
    u16* Wfh = (u16*)(ws + 4 * SZ);                          // 96 KB (pad 128K)
    u16* Wfl = (u16*)(ws + 4 * SZ + (128 << 10));

    prep_kernel<<<dim3(536), 256, 0, stream>>>(WQ, WK, WV, Tbl, Wfh, Wfl);
    proj_kernel<<<dim3(256), 512, 0, stream>>>(
        X, Tbl, Wfh, Wfl, Qb, Kb, Vb);
    retention_kernel<<<dim3(64, NB), 1024, 0, stream>>>(
        Qb, Kb, Vb, Out);
}

// Round 9
// 34.008 us; speedup vs baseline: 1.5286x; 1.0607x over previous
//
#include <hip/hip_runtime.h>
#include <hip/hip_bf16.h>
#include <math.h>

// SimpleRetention on MI355X, round 9.
// out = (Q K^T ∘ D) V, D[n,m]=gamma^(n-m)[n>=m], gamma=0.96875.
// Banded: gamma^513 ~ 8e-8 -> window of 8 previous 64-tiles + diagonal.
// proj v7: 1024 thr/block (4 waves/SIMD), 64 rows, X hi/lo 3-term MFMA.
// retention v7: ONE barrier/tile (K dbuf, V 3-ring, S dbuf; r6 staging
//               discipline with K kept in LDS), stride-72 everywhere.

#define SEQ    4096
#define NB     4
#define HID    256
#define HD     64
#define WT     8

typedef short          bf16x8 __attribute__((ext_vector_type(8)));
typedef float          f32x4  __attribute__((ext_vector_type(4)));
typedef unsigned short u16;
typedef unsigned int   u32;
typedef u16            u16x8  __attribute__((ext_vector_type(8)));
typedef u16            u16x4  __attribute__((ext_vector_type(4)));

__device__ __forceinline__ u16 f2bf(float f) {
    __hip_bfloat16 h = __float2bfloat16(f);
    return __builtin_bit_cast(u16, h);
}
__device__ __forceinline__ float bf2f(u16 b) {
    __hip_bfloat16 h = __builtin_bit_cast(__hip_bfloat16, b);
    return __bfloat162float(h);
}

// ---------------------------------------------------------------------------
// Prep: xPos table (blocks 0..511) + W fragment swizzle hi/lo (blocks 512..535).
// Wf frag f = ((ct*8 + kc)*64 + lane): b[j] = W[kc*32+(lane>>4)*8+j][ct*16+(lane&15)]
// ---------------------------------------------------------------------------
__global__ __launch_bounds__(256)
void prep_kernel(const float* __restrict__ WQ, const float* __restrict__ WK,
                 const float* __restrict__ WV, float* __restrict__ Tbl,
                 u16* __restrict__ Wfh, u16* __restrict__ Wfl)
{
    const int t = threadIdx.x;
    if (blockIdx.x < 512) {
        const int p = blockIdx.x * 256 + t;
        const int n = p >> 5, i = p & 31;
        const float sv = (2.f * (float)i + 25.6f) / 89.6f;
        const float sc = powf(sv, (float)n * (1.f / 512.f));
        const float inv_freq = 1.f / powf(10000.f, (float)i * (1.f / 32.f));
        float sn, cs;
        sincosf((float)n * inv_freq, &sn, &cs);
        float4 o;
        o.x = cs * sc; o.y = sn * sc;   // Q (downscale=False)
        o.z = cs / sc; o.w = sn / sc;   // K (downscale=True)
        reinterpret_cast<float4*>(Tbl)[p] = o;
    } else {
        const int p = (blockIdx.x - 512) * 256 + t;   // 0..6143
        const int lane = p & 63;
        const int kc   = (p >> 6) & 7;
        const int ct   = p >> 9;                      // 0..11
        const int col  = ct * 16 + (lane & 15);
        const float* Wsrc = (col < 64) ? WQ : (col < 128) ? WK : WV;
        const int c = col & 63;
        u16x8 hv, lv;
#pragma unroll
        for (int j = 0; j < 8; ++j) {
            const float w = Wsrc[(kc * 32 + (lane >> 4) * 8 + j) * HD + c];
            hv[j] = f2bf(w);
            lv[j] = f2bf(w - bf2f(hv[j]));
        }
        *reinterpret_cast<u16x8*>(&Wfh[(size_t)p * 8]) = hv;
        *reinterpret_cast<u16x8*>(&Wfl[(size_t)p * 8]) = lv;
    }
}

// ---------------------------------------------------------------------------
// Projection + fused xPos. 256 blocks x 1024 thr, 64 rows/block.
// 16 waves: wave (rt,ch) does 1 row-tile x 3 col-tiles (72 MFMA).
// X converted to hi/lo bf16 once into LDS. Q/K/V emitted plain bf16.
// ---------------------------------------------------------------------------
#define XLDS 264   // u16 row stride: 16B-aligned, 2-way bank alias (free)

__global__ __launch_bounds__(1024, 4)
void proj_kernel(const float* __restrict__ X, const float* __restrict__ Tbl,
                 const u16* __restrict__ Wfh, const u16* __restrict__ Wfl,
                 u16* __restrict__ Qb, u16* __restrict__ Kb, u16* __restrict__ Vb)
{
    __shared__ __align__(16) u16 Xhs[64 * XLDS];
    __shared__ __align__(16) u16 Xls[64 * XLDS];
    const int t = threadIdx.x;
    const int row0 = blockIdx.x * 64;

    // stage X tile as bf16 hi/lo (convert once per block)
    for (int e = t; e < 64 * 64; e += 1024) {
        const int r = e >> 6, k4 = (e & 63) << 2;
        const float4 xv = *reinterpret_cast<const float4*>(&X[(size_t)(row0 + r) * HID + k4]);
        u16x4 hv, lv;
#pragma unroll
        for (int j = 0; j < 4; ++j) {
            const float f = (&xv.x)[j];
            hv[j] = f2bf(f);
            lv[j] = f2bf(f - bf2f(hv[j]));
        }
        *reinterpret_cast<u16x4*>(&Xhs[r * XLDS + k4]) = hv;
        *reinterpret_cast<u16x4*>(&Xls[r * XLDS + k4]) = lv;
    }
    __syncthreads();

    const int lane = t & 63;
    const int w    = t >> 6;    // 0..15
    const int rt   = w >> 2;    // 0..3 : 16-row tile
    const int ch   = w & 3;     // 0..3 : 3 col-tiles each
    const int frow = rt * 16 + (lane & 15);
    const int fk   = (lane >> 4) * 8;

    f32x4 acc[3];
#pragma unroll
    for (int i = 0; i < 3; ++i) acc[i] = (f32x4)0.f;

#pragma unroll
    for (int kc = 0; kc < 8; ++kc) {
        const bf16x8 ah = *reinterpret_cast<const bf16x8*>(&Xhs[frow * XLDS + kc * 32 + fk]);
        const bf16x8 al = *reinterpret_cast<const bf16x8*>(&Xls[frow * XLDS + kc * 32 + fk]);
#pragma unroll
        for (int ctp = 0; ctp < 3; ++ctp) {
            const int ct = ch * 3 + ctp;
            const size_t fb = (size_t)((ct * 8 + kc) * 64 + lane) * 8;
            const bf16x8 wh = *reinterpret_cast<const bf16x8*>(&Wfh[fb]);
            const bf16x8 wl = *reinterpret_cast<const bf16x8*>(&Wfl[fb]);
            acc[ctp] = __builtin_amdgcn_mfma_f32_16x16x32_bf16(ah, wh, acc[ctp], 0, 0, 0);
            acc[ctp] = __builtin_amdgcn_mfma_f32_16x16x32_bf16(al, wh, acc[ctp], 0, 0, 0);
            acc[ctp] = __builtin_amdgcn_mfma_f32_16x16x32_bf16(ah, wl, acc[ctp], 0, 0, 0);
        }
    }

    // emit: pair adjacent columns (2i,2i+1) -> u32 stores (plain bf16).
    // even lanes handle regs 0-1, odd lanes regs 2-3 (both columns of the pair).
    const int sel   = lane & 1;
    const int c16   = lane & 15;
    const int rbase = (lane >> 4) * 4;

#pragma unroll
    for (int ctp = 0; ctp < 3; ++ctp) {
        const int ct = ch * 3 + ctp;
        float xp[4];
#pragma unroll
        for (int reg = 0; reg < 4; ++reg)
            xp[reg] = __shfl_xor(acc[ctp][reg], 1, 64);
#pragma unroll
        for (int rr = 0; rr < 2; ++rr) {
            const int reg = sel * 2 + rr;
            const float xe = sel ? xp[reg] : acc[ctp][reg];   // even-col value
            const float xo = sel ? acc[ctp][reg] : xp[reg];   // odd-col value
            const int r = row0 + rt * 16 + rbase + reg;
            if (ct < 8) {
                const bool isK = ct >= 4;
                const int cq0 = (ct & 3) * 16 + (c16 & ~1);
                const int i   = cq0 >> 1;
                const int n   = r & (SEQ - 1);
                const float4 tb = reinterpret_cast<const float4*>(Tbl)[n * 32 + i];
                const float cs = isK ? tb.z : tb.x;
                const float sn = isK ? tb.w : tb.y;
                const float oe = xe * cs - xo * sn;
                const float oo = xo * cs + xe * sn;
                const u32 hw = (u32)f2bf(oe) | ((u32)f2bf(oo) << 16);
                u32* P = reinterpret_cast<u32*>(isK ? Kb : Qb);
                P[(r * HD + cq0) >> 1] = hw;
            } else {
                const int cv0 = (ct - 8) * 16 + (c16 & ~1);
                const u32 w32 = (u32)f2bf(xe) | ((u32)f2bf(xo) << 16);
                reinterpret_cast<u32*>(Vb)[(r * HD + cv0) >> 1] = w32;
            }
        }
    }
}

// ---------------------------------------------------------------------------
// Banded retention. 256 blocks x 1024 thr. Wave (rb,cb) owns a 16x16 tile.
// ONE barrier per tile: K dbuf, V 3-ring (read after barrier -> needs 2-barrier
// read->overwrite distance), S dbuf. Staging: global->reg in s1, LDS-write in
// s4 into NEXT tile's slot. Q frags global->reg once. 63 KB LDS.
// ---------------------------------------------------------------------------
#define KRS 72
#define SW  72

__global__ __launch_bounds__(1024, 4)
void retention_kernel(const u16* __restrict__ Qb, const u16* __restrict__ Kb,
                      const u16* __restrict__ Vb, float* __restrict__ Out)
{
    __shared__ __align__(16) u16 Khs[2][64 * KRS];
    __shared__ __align__(16) u16 Vts[3][64 * KRS];
    __shared__ __align__(16) u16 Ss [2][64 * SW];

    const int t    = threadIdx.x;
    const int lane = t & 63;
    const int w    = t >> 6;       // 0..15
    const int rb   = w >> 2;       // 0..3 : 16-row strip of S/O
    const int cb   = w & 3;        // 0..3 : 16-col strip

    // XCD swizzle: bijective for 256 blocks / 8 XCDs
    const int flat = blockIdx.x + 64 * blockIdx.y;
    const int work = (flat & 7) * 32 + (flat >> 3);
    const int nt   = work & 63;
    const int b    = work >> 6;
    const int n0   = nt * 64;
    const int bbase = b * SEQ;

    // staging roles: half 0 -> K; half 1 -> V (each 512 thr, one b128 per tile)
    const int half = t >> 9;
    const int th   = t & 511;
    const int srow = th >> 3;           // 0..63
    const int scol = (th & 7) * 8;
    const int vch  = ((srow >> 3) ^ (th & 7)) & 7;   // (m>>3) ^ (v>>3)
    const int vidx = vch * 8 + (srow & 7);

    const int mt0 = (nt >= WT) ? (nt - WT) : 0;

    // ---- prologue: stage first K/V tile into slot 0; Q frags from global ----
    {
        const int gk = (bbase + mt0 * 64 + srow) * HD + scol;
        if (half == 0) {
            *reinterpret_cast<u16x8*>(&Khs[0][srow * KRS + scol]) =
                *reinterpret_cast<const u16x8*>(&Kb[gk]);
        } else {
            const u16x8 vv = *reinterpret_cast<const u16x8*>(&Vb[gk]);
#pragma unroll
            for (int j = 0; j < 8; ++j)
                Vts[0][(scol + j) * KRS + vidx] = vv[j];
        }
    }

    const int frow = rb * 16 + (lane & 15);
    const int fk   = (lane >> 4) * 8;
    const size_t gq = (size_t)(bbase + n0 + frow) * HD + fk;
    const bf16x8 qb0 = *reinterpret_cast<const bf16x8*>(&Qb[gq]);
    const bf16x8 qb1 = *reinterpret_cast<const bf16x8*>(&Qb[gq + 32]);
    __syncthreads();

    // per-lane decay constants: gamma^d = gamma^(n0-m0) * gamma^(nloc-mloc)
    const float log2g = -0.04580368544f;   // log2(0.96875)
    const int nlocB = rb * 16 + (lane >> 4) * 4;
    const int mloc  = cb * 16 + (lane & 15);
    float gd[4]; int dd[4];
#pragma unroll
    for (int reg = 0; reg < 4; ++reg) {
        dd[reg] = nlocB + reg - mloc;
        gd[reg] = exp2f((float)dd[reg] * log2g);
    }

    f32x4 accO = (f32x4)0.f;
    const int mrow = cb * 16 + (lane & 15);
    const int c0 = ((lane >> 4)     ^ (mrow >> 3)) & 7;
    const int c1 = (((lane >> 4) + 4) ^ (mrow >> 3)) & 7;

    int curV = 0;
    for (int mt = mt0, i = 0; mt <= nt; ++mt, ++i) {
        const int cur  = i & 1;
        const int m0   = mt * 64;
        const bool pref = (mt < nt);
        const int wV   = (curV == 2) ? 0 : curV + 1;   // next V ring slot

        // s1. issue next-tile global loads (in flight under QK^T)
        u16x8 pk, pv;
        if (pref) {
            const int gk = (bbase + m0 + 64 + srow) * HD + scol;
            if (half == 0) pk = *reinterpret_cast<const u16x8*>(&Kb[gk]);
            else           pv = *reinterpret_cast<const u16x8*>(&Vb[gk]);
        }

        // s2. S = Q K^T (plain bf16, 2 MFMA), 16x16 per wave
        const bf16x8 kb0 = *reinterpret_cast<const bf16x8*>(&Khs[cur][mrow * KRS + fk]);
        const bf16x8 kb1 = *reinterpret_cast<const bf16x8*>(&Khs[cur][mrow * KRS + 32 + fk]);
        f32x4 accS = (f32x4)0.f;
        accS = __builtin_amdgcn_mfma_f32_16x16x32_bf16(qb0, kb0, accS, 0, 0, 0);
        accS = __builtin_amdgcn_mfma_f32_16x16x32_bf16(qb1, kb1, accS, 0, 0, 0);

        // s3. decay + mask + bf16 -> Ss[cur]
        const float gs = exp2f((float)(n0 - m0) * log2g);
#pragma unroll
        for (int reg = 0; reg < 4; ++reg) {
            const int d   = (n0 - m0) + dd[reg];
            const float g = (d >= 0) ? gs * gd[reg] : 0.f;
            Ss[cur][(nlocB + reg) * SW + mloc] = f2bf(accS[reg] * g);
        }

        // s4. write prefetched K/V -> next slots
        if (pref) {
            if (half == 0) {
                *reinterpret_cast<u16x8*>(&Khs[cur ^ 1][srow * KRS + scol]) = pk;
            } else {
#pragma unroll
                for (int j = 0; j < 8; ++j)
                    Vts[wV][(scol + j) * KRS + vidx] = pv[j];
            }
        }

        __syncthreads();   // single barrier: Ss[cur]/Vts[curV] ready for SV;
                           // next K/V staged for iteration i+1

        // s5. O += S V
        const bf16x8 s0 = *reinterpret_cast<const bf16x8*>(&Ss[cur][frow * SW + fk]);
        const bf16x8 s1 = *reinterpret_cast<const bf16x8*>(&Ss[cur][frow * SW + 32 + fk]);
        const bf16x8 v0 = *reinterpret_cast<const bf16x8*>(&Vts[curV][mrow * KRS + c0 * 8]);
        const bf16x8 v1 = *reinterpret_cast<const bf16x8*>(&Vts[curV][mrow * KRS + c1 * 8]);
        accO = __builtin_amdgcn_mfma_f32_16x16x32_bf16(s0, v0, accO, 0, 0, 0);
        accO = __builtin_amdgcn_mfma_f32_16x16x32_bf16(s1, v1, accO, 0, 0, 0);

        curV = wV;
    }

    // write output (fp32)
    const int v = cb * 16 + (lane & 15);
#pragma unroll
    for (int reg = 0; reg < 4; ++reg) {
        const int n = n0 + rb * 16 + (lane >> 4) * 4 + reg;
        Out[(size_t)(bbase + n) * HD + v] = accO[reg];
    }
}

// ---------------------------------------------------------------------------
extern "C" void kernel_launch(void* const* d_in, const int* in_sizes, int n_in,
                              void* d_out, int out_size, void* d_ws, size_t ws_size,
                              hipStream_t stream)
{
    const float* X  = (const float*)d_in[0];
    const float* WQ = (const float*)d_in[1];
    const float* WK = (const float*)d_in[2];
    const float* WV = (const float*)d_in[3];
    float* Out = (float*)d_out;

    char* ws = (char*)d_ws;
    const size_t SZ = (size_t)NB * SEQ * HD * sizeof(u16);   // 2 MB
    u16* Qb = (u16*)(ws);
    u16* Kb = (u16*)(ws + SZ);
    u16* Vb = (u16*)(ws + 2 * SZ);
    float* Tbl = (float*)(ws + 3 * SZ);                      // 2 MB
    u16* Wfh = (u16*)(ws + 4 * SZ);                          // 96 KB (pad 128K)
    u16* Wfl = (u16*)(ws + 4 * SZ + (128 << 10));

    prep_kernel<<<dim3(536), 256, 0, stream>>>(WQ, WK, WV, Tbl, Wfh, Wfl);
    proj_kernel<<<dim3(256), 1024, 0, stream>>>(
        X, Tbl, Wfh, Wfl, Qb, Kb, Vb);
    retention_kernel<<<dim3(64, NB), 1024, 0, stream>>>(
        Qb, Kb, Vb, Out);
}

// Round 10
// 28.463 us; speedup vs baseline: 1.8265x; 1.1949x over previous
//
#include <hip/hip_runtime.h>
#include <hip/hip_bf16.h>
#include <math.h>

// SimpleRetention on MI355X, round 10.
// out = (Q K^T ∘ D) V, D[n,m]=gamma^(n-m)[n>=m], gamma=0.96875.
// Banded: WT=4 -> min excluded distance 257, gamma^257=2.9e-4; excluded-tail
// absmax contribution ~1e-5 (20x below bf16 quantization floor).
// proj v8: single-term plain-bf16 MFMA (Q/K/V stored bf16 anyway).
// retention v7 (r9): ONE barrier/tile, K dbuf, V 3-ring, S dbuf, stride-72.

#define SEQ    4096
#define NB     4
#define HID    256
#define HD     64
#define WT     4

typedef short          bf16x8 __attribute__((ext_vector_type(8)));
typedef float          f32x4  __attribute__((ext_vector_type(4)));
typedef unsigned short u16;
typedef unsigned int   u32;
typedef u16            u16x8  __attribute__((ext_vector_type(8)));
typedef u16            u16x4  __attribute__((ext_vector_type(4)));

__device__ __forceinline__ u16 f2bf(float f) {
    __hip_bfloat16 h = __float2bfloat16(f);
    return __builtin_bit_cast(u16, h);
}

// ---------------------------------------------------------------------------
// Prep: xPos table (blocks 0..511) + W fragment swizzle (blocks 512..535).
// Wf frag f = ((ct*8 + kc)*64 + lane): b[j] = W[kc*32+(lane>>4)*8+j][ct*16+(lane&15)]
// ---------------------------------------------------------------------------
__global__ __launch_bounds__(256)
void prep_kernel(const float* __restrict__ WQ, const float* __restrict__ WK,
                 const float* __restrict__ WV, float* __restrict__ Tbl,
                 u16* __restrict__ Wf)
{
    const int t = threadIdx.x;
    if (blockIdx.x < 512) {
        const int p = blockIdx.x * 256 + t;
        const int n = p >> 5, i = p & 31;
        const float sv = (2.f * (float)i + 25.6f) / 89.6f;
        const float sc = powf(sv, (float)n * (1.f / 512.f));
        const float inv_freq = 1.f / powf(10000.f, (float)i * (1.f / 32.f));
        float sn, cs;
        sincosf((float)n * inv_freq, &sn, &cs);
        float4 o;
        o.x = cs * sc; o.y = sn * sc;   // Q (downscale=False)
        o.z = cs / sc; o.w = sn / sc;   // K (downscale=True)
        reinterpret_cast<float4*>(Tbl)[p] = o;
    } else {
        const int p = (blockIdx.x - 512) * 256 + t;   // 0..6143
        const int lane = p & 63;
        const int kc   = (p >> 6) & 7;
        const int ct   = p >> 9;                      // 0..11
        const int col  = ct * 16 + (lane & 15);
        const float* Wsrc = (col < 64) ? WQ : (col < 128) ? WK : WV;
        const int c = col & 63;
        u16x8 hv;
#pragma unroll
        for (int j = 0; j < 8; ++j)
            hv[j] = f2bf(Wsrc[(kc * 32 + (lane >> 4) * 8 + j) * HD + c]);
        *reinterpret_cast<u16x8*>(&Wf[(size_t)p * 8]) = hv;
    }
}

// ---------------------------------------------------------------------------
// Projection + fused xPos. 256 blocks x 1024 thr, 64 rows/block.
// 16 waves: wave (rt,ch) does 1 row-tile x 3 col-tiles, single-term bf16.
// ---------------------------------------------------------------------------
#define XLDS 264   // u16 row stride: 16B-aligned, 2-way bank alias (free)

__global__ __launch_bounds__(1024, 4)
void proj_kernel(const float* __restrict__ X, const float* __restrict__ Tbl,
                 const u16* __restrict__ Wf,
                 u16* __restrict__ Qb, u16* __restrict__ Kb, u16* __restrict__ Vb)
{
    __shared__ __align__(16) u16 Xhs[64 * XLDS];
    const int t = threadIdx.x;
    const int row0 = blockIdx.x * 64;

    // stage X tile as bf16 (convert once per block)
    for (int e = t; e < 64 * 64; e += 1024) {
        const int r = e >> 6, k4 = (e & 63) << 2;
        const float4 xv = *reinterpret_cast<const float4*>(&X[(size_t)(row0 + r) * HID + k4]);
        u16x4 hv;
#pragma unroll
        for (int j = 0; j < 4; ++j) hv[j] = f2bf((&xv.x)[j]);
        *reinterpret_cast<u16x4*>(&Xhs[r * XLDS + k4]) = hv;
    }
    __syncthreads();

    const int lane = t & 63;
    const int w    = t >> 6;    // 0..15
    const int rt   = w >> 2;    // 0..3 : 16-row tile
    const int ch   = w & 3;     // 0..3 : 3 col-tiles each
    const int frow = rt * 16 + (lane & 15);
    const int fk   = (lane >> 4) * 8;

    f32x4 acc[3];
#pragma unroll
    for (int i = 0; i < 3; ++i) acc[i] = (f32x4)0.f;

#pragma unroll
    for (int kc = 0; kc < 8; ++kc) {
        const bf16x8 ah = *reinterpret_cast<const bf16x8*>(&Xhs[frow * XLDS + kc * 32 + fk]);
#pragma unroll
        for (int ctp = 0; ctp < 3; ++ctp) {
            const int ct = ch * 3 + ctp;
            const size_t fb = (size_t)((ct * 8 + kc) * 64 + lane) * 8;
            const bf16x8 wh = *reinterpret_cast<const bf16x8*>(&Wf[fb]);
            acc[ctp] = __builtin_amdgcn_mfma_f32_16x16x32_bf16(ah, wh, acc[ctp], 0, 0, 0);
        }
    }

    // emit: pair adjacent columns (2i,2i+1) -> u32 stores (plain bf16).
    // even lanes handle regs 0-1, odd lanes regs 2-3 (both columns of the pair).
    const int sel   = lane & 1;
    const int c16   = lane & 15;
    const int rbase = (lane >> 4) * 4;

#pragma unroll
    for (int ctp = 0; ctp < 3; ++ctp) {
        const int ct = ch * 3 + ctp;
        float xp[4];
#pragma unroll
        for (int reg = 0; reg < 4; ++reg)
            xp[reg] = __shfl_xor(acc[ctp][reg], 1, 64);
#pragma unroll
        for (int rr = 0; rr < 2; ++rr) {
            const int reg = sel * 2 + rr;
            const float xe = sel ? xp[reg] : acc[ctp][reg];   // even-col value
            const float xo = sel ? acc[ctp][reg] : xp[reg];   // odd-col value
            const int r = row0 + rt * 16 + rbase + reg;
            if (ct < 8) {
                const bool isK = ct >= 4;
                const int cq0 = (ct & 3) * 16 + (c16 & ~1);
                const int i   = cq0 >> 1;
                const int n   = r & (SEQ - 1);
                const float4 tb = reinterpret_cast<const float4*>(Tbl)[n * 32 + i];
                const float cs = isK ? tb.z : tb.x;
                const float sn = isK ? tb.w : tb.y;
                const float oe = xe * cs - xo * sn;
                const float oo = xo * cs + xe * sn;
                const u32 hw = (u32)f2bf(oe) | ((u32)f2bf(oo) << 16);
                u32* P = reinterpret_cast<u32*>(isK ? Kb : Qb);
                P[(r * HD + cq0) >> 1] = hw;
            } else {
                const int cv0 = (ct - 8) * 16 + (c16 & ~1);
                const u32 w32 = (u32)f2bf(xe) | ((u32)f2bf(xo) << 16);
                reinterpret_cast<u32*>(Vb)[(r * HD + cv0) >> 1] = w32;
            }
        }
    }
}

// ---------------------------------------------------------------------------
// Banded retention. 256 blocks x 1024 thr. Wave (rb,cb) owns a 16x16 tile.
// ONE barrier per tile: K dbuf, V 3-ring, S dbuf. Staging: global->reg in s1,
// LDS-write in s4 into NEXT slot. Q frags global->reg once. 63 KB LDS.
// ---------------------------------------------------------------------------
#define KRS 72
#define SW  72

__global__ __launch_bounds__(1024, 4)
void retention_kernel(const u16* __restrict__ Qb, const u16* __restrict__ Kb,
                      const u16* __restrict__ Vb, float* __restrict__ Out)
{
    __shared__ __align__(16) u16 Khs[2][64 * KRS];
    __shared__ __align__(16) u16 Vts[3][64 * KRS];
    __shared__ __align__(16) u16 Ss [2][64 * SW];

    const int t    = threadIdx.x;
    const int lane = t & 63;
    const int w    = t >> 6;       // 0..15
    const int rb   = w >> 2;       // 0..3 : 16-row strip of S/O
    const int cb   = w & 3;        // 0..3 : 16-col strip

    // XCD swizzle: bijective for 256 blocks / 8 XCDs
    const int flat = blockIdx.x + 64 * blockIdx.y;
    const int work = (flat & 7) * 32 + (flat >> 3);
    const int nt   = work & 63;
    const int b    = work >> 6;
    const int n0   = nt * 64;
    const int bbase = b * SEQ;

    // staging roles: half 0 -> K; half 1 -> V (each 512 thr, one b128 per tile)
    const int half = t >> 9;
    const int th   = t & 511;
    const int srow = th >> 3;           // 0..63
    const int scol = (th & 7) * 8;
    const int vch  = ((srow >> 3) ^ (th & 7)) & 7;   // (m>>3) ^ (v>>3)
    const int vidx = vch * 8 + (srow & 7);

    const int mt0 = (nt >= WT) ? (nt - WT) : 0;

    // ---- prologue: stage first K/V tile into slot 0; Q frags from global ----
    {
        const int gk = (bbase + mt0 * 64 + srow) * HD + scol;
        if (half == 0) {
            *reinterpret_cast<u16x8*>(&Khs[0][srow * KRS + scol]) =
                *reinterpret_cast<const u16x8*>(&Kb[gk]);
        } else {
            const u16x8 vv = *reinterpret_cast<const u16x8*>(&Vb[gk]);
#pragma unroll
            for (int j = 0; j < 8; ++j)
                Vts[0][(scol + j) * KRS + vidx] = vv[j];
        }
    }

    const int frow = rb * 16 + (lane & 15);
    const int fk   = (lane >> 4) * 8;
    const size_t gq = (size_t)(bbase + n0 + frow) * HD + fk;
    const bf16x8 qb0 = *reinterpret_cast<const bf16x8*>(&Qb[gq]);
    const bf16x8 qb1 = *reinterpret_cast<const bf16x8*>(&Qb[gq + 32]);
    __syncthreads();

    // per-lane decay constants: gamma^d = gamma^(n0-m0) * gamma^(nloc-mloc)
    const float log2g = -0.04580368544f;   // log2(0.96875)
    const int nlocB = rb * 16 + (lane >> 4) * 4;
    const int mloc  = cb * 16 + (lane & 15);
    float gd[4]; int dd[4];
#pragma unroll
    for (int reg = 0; reg < 4; ++reg) {
        dd[reg] = nlocB + reg - mloc;
        gd[reg] = exp2f((float)dd[reg] * log2g);
    }

    f32x4 accO = (f32x4)0.f;
    const int mrow = cb * 16 + (lane & 15);
    const int c0 = ((lane >> 4)     ^ (mrow >> 3)) & 7;
    const int c1 = (((lane >> 4) + 4) ^ (mrow >> 3)) & 7;

    int curV = 0;
    for (int mt = mt0, i = 0; mt <= nt; ++mt, ++i) {
        const int cur  = i & 1;
        const int m0   = mt * 64;
        const bool pref = (mt < nt);
        const int wV   = (curV == 2) ? 0 : curV + 1;   // next V ring slot

        // s1. issue next-tile global loads (in flight under QK^T)
        u16x8 pk, pv;
        if (pref) {
            const int gk = (bbase + m0 + 64 + srow) * HD + scol;
            if (half == 0) pk = *reinterpret_cast<const u16x8*>(&Kb[gk]);
            else           pv = *reinterpret_cast<const u16x8*>(&Vb[gk]);
        }

        // s2. S = Q K^T (plain bf16, 2 MFMA), 16x16 per wave
        const bf16x8 kb0 = *reinterpret_cast<const bf16x8*>(&Khs[cur][mrow * KRS + fk]);
        const bf16x8 kb1 = *reinterpret_cast<const bf16x8*>(&Khs[cur][mrow * KRS + 32 + fk]);
        f32x4 accS = (f32x4)0.f;
        accS = __builtin_amdgcn_mfma_f32_16x16x32_bf16(qb0, kb0, accS, 0, 0, 0);
        accS = __builtin_amdgcn_mfma_f32_16x16x32_bf16(qb1, kb1, accS, 0, 0, 0);

        // s3. decay + mask + bf16 -> Ss[cur]
        const float gs = exp2f((float)(n0 - m0) * log2g);
#pragma unroll
        for (int reg = 0; reg < 4; ++reg) {
            const int d   = (n0 - m0) + dd[reg];
            const float g = (d >= 0) ? gs * gd[reg] : 0.f;
            Ss[cur][(nlocB + reg) * SW + mloc] = f2bf(accS[reg] * g);
        }

        // s4. write prefetched K/V -> next slots
        if (pref) {
            if (half == 0) {
                *reinterpret_cast<u16x8*>(&Khs[cur ^ 1][srow * KRS + scol]) = pk;
            } else {
#pragma unroll
                for (int j = 0; j < 8; ++j)
                    Vts[wV][(scol + j) * KRS + vidx] = pv[j];
            }
        }

        __syncthreads();   // single barrier: Ss[cur]/Vts[curV] ready for SV;
                           // next K/V staged for iteration i+1

        // s5. O += S V
        const bf16x8 s0 = *reinterpret_cast<const bf16x8*>(&Ss[cur][frow * SW + fk]);
        const bf16x8 s1 = *reinterpret_cast<const bf16x8*>(&Ss[cur][frow * SW + 32 + fk]);
        const bf16x8 v0 = *reinterpret_cast<const bf16x8*>(&Vts[curV][mrow * KRS + c0 * 8]);
        const bf16x8 v1 = *reinterpret_cast<const bf16x8*>(&Vts[curV][mrow * KRS + c1 * 8]);
        accO = __builtin_amdgcn_mfma_f32_16x16x32_bf16(s0, v0, accO, 0, 0, 0);
        accO = __builtin_amdgcn_mfma_f32_16x16x32_bf16(s1, v1, accO, 0, 0, 0);

        curV = wV;
    }

    // write output (fp32)
    const int v = cb * 16 + (lane & 15);
#pragma unroll
    for (int reg = 0; reg < 4; ++reg) {
        const int n = n0 + rb * 16 + (lane >> 4) * 4 + reg;
        Out[(size_t)(bbase + n) * HD + v] = accO[reg];
    }
}

// ---------------------------------------------------------------------------
extern "C" void kernel_launch(void* const* d_in, const int* in_sizes, int n_in,
                              void* d_out, int out_size, void* d_ws, size_t ws_size,
                              hipStream_t stream)
{
    const float* X  = (const float*)d_in[0];
    const float* WQ = (const float*)d_in[1];
    const float* WK = (const float*)d_in[2];
    const float* WV = (const float*)d_in[3];
    float* Out = (float*)d_out;

    char* ws = (char*)d_ws;
    const size_t SZ = (size_t)NB * SEQ * HD * sizeof(u16);   // 2 MB
    u16* Qb = (u16*)(ws);
    u16* Kb = (u16*)(ws + SZ);
    u16* Vb = (u16*)(ws + 2 * SZ);
    float* Tbl = (float*)(ws + 3 * SZ);                      // 2 MB
    u16* Wf = (u16*)(ws + 4 * SZ);                           // 96 KB

    prep_kernel<<<dim3(536), 256, 0, stream>>>(WQ, WK, WV, Tbl, Wf);
    proj_kernel<<<dim3(256), 1024, 0, stream>>>(
        X, Tbl, Wf, Qb, Kb, Vb);
    retention_kernel<<<dim3(64, NB), 1024, 0, stream>>>(
        Qb, Kb, Vb, Out);
}